// Round 8
// baseline (339.559 us; speedup 1.0000x reference)
//
#include <hip/hip_runtime.h>
#include <math.h>

#define NN 8192        // n_nodes
#define NE 262144      // edges per adjacency list
#define TOTAL (2*NE)   // 524288
#define NSEG 2         // column segments per row
#define HALF 4096      // columns per segment
#define SCAP 64        // bucket capacity per (row,seg): mean 32, sd 5.7, max ~58

typedef float f4 __attribute__((ext_vector_type(4)));

struct Pair { int c; float v; };   // c = column local to segment

// Workspace layout (bytes):
//   [0, 65536)                cnt[NN*NSEG] bucket cursors
//   [65536, 98304)            rowsum[NN]
//   [98304, 98308)            ovf_cnt
//   [131072, 131072+8MB)      bucket Pair[NN*NSEG][SCAP]
//   [131072+8MB, +128KB)      ovf int4[8192] (r, global c, bits(w*v), 0)
#define RS_OFF  65536
#define OC_OFF  98304
#define BK_OFF  131072
#define OV_OFF  (131072 + (size_t)NN * NSEG * SCAP * 8)

// Single pass: blend weight, accumulate exact row sum (same addend multiset
// as the reference's dense row sum), scatter into column-segmented buckets.
__global__ __launch_bounds__(256) void fill_kernel(
        const int* __restrict__ rows_s, const int* __restrict__ cols_s,
        const float* __restrict__ vals_s,
        const int* __restrict__ rows_t, const int* __restrict__ cols_t,
        const float* __restrict__ vals_t,
        const float* __restrict__ gamma,
        int* __restrict__ cnt, float* __restrict__ rowsum,
        Pair* __restrict__ bucket,
        int* __restrict__ ovf_cnt, int4* __restrict__ ovf) {
    int i = blockIdx.x * blockDim.x + threadIdx.x;
    float alpha = 1.0f / (1.0f + expf(-gamma[0]));
    int r, c; float v, w;
    if (i < NE) { r = rows_s[i]; c = cols_s[i]; v = vals_s[i]; w = alpha; }
    else { int j = i - NE; r = rows_t[j]; c = cols_t[j]; v = vals_t[j]; w = 1.0f - alpha; }
    float wv = w * v;
    atomicAdd(&rowsum[r], wv);                 // L2-resident 32 KB array
    int b = r * NSEG + (c >> 12);
    int pos = atomicAdd(&cnt[b], 1);
    if (pos < SCAP) {
        Pair p; p.c = c & (HALF - 1); p.v = wv;
        bucket[b * SCAP + pos] = p;
    } else {  // P ~ 3e-4 per run; kept for correctness
        int k = atomicAdd(ovf_cnt, 1);
        int4 e; e.x = r; e.y = c; e.z = __float_as_int(wv); e.w = 0;
        ovf[k] = e;
    }
}

// One block per (row, segment). Zero 16 KB LDS, scatter own ~32 entries,
// one barrier, scale by precomputed 1/rowsum, NONTEMPORAL f4 stream-out
// (R7 lesson: plain stores thrash L2 with the 268 MB stream, +25 us).
__global__ __launch_bounds__(256) void row_kernel(
        const int* __restrict__ cnt, const float* __restrict__ rowsum,
        const Pair* __restrict__ bucket,
        const int* __restrict__ ovf_cnt, const int4* __restrict__ ovf,
        float* __restrict__ out) {
    __shared__ float row[HALF];        // 16 KB -> 8 blocks/CU (wave-capped)
    int b   = blockIdx.x;
    int r   = b >> 1;
    int seg = b & 1;
    int t   = threadIdx.x;

    f4* row4 = (f4*)row;
    #pragma unroll
    for (int k = t; k < HALF / 4; k += 256) { f4 z = {0.f, 0.f, 0.f, 0.f}; row4[k] = z; }
    int n  = cnt[b];
    int nb = n < SCAP ? n : SCAP;
    float rs = rowsum[r];
    __syncthreads();

    for (int k = t; k < nb; k += 256) {        // one iteration, ~32 lanes active
        Pair p = bucket[b * SCAP + k];
        atomicAdd(&row[p.c], p.v);
    }
    int no = *ovf_cnt;
    if (no > 0) {                              // cold path, normally 0 entries
        for (int k = t; k < no; k += 256) {
            int4 e = ovf[k];
            if (e.x == r && (e.y >> 12) == seg)
                atomicAdd(&row[e.y & (HALF - 1)], __int_as_float(e.z));
        }
    }
    __syncthreads();                           // fences LDS scatter atomics

    float inv = (rs == 0.0f) ? 1.0f : 1.0f / rs;
    f4* out4 = (f4*)(out + (size_t)r * NN + seg * HALF);
    #pragma unroll
    for (int k = t; k < HALF / 4; k += 256) {
        f4 x = row4[k];
        x *= inv;
        __builtin_nontemporal_store(x, &out4[k]);
    }
}

extern "C" void kernel_launch(void* const* d_in, const int* in_sizes, int n_in,
                              void* d_out, int out_size, void* d_ws, size_t ws_size,
                              hipStream_t stream) {
    const int*   rows_s = (const int*)  d_in[0];
    const int*   cols_s = (const int*)  d_in[1];
    const float* vals_s = (const float*)d_in[2];
    const int*   rows_t = (const int*)  d_in[3];
    const int*   cols_t = (const int*)  d_in[4];
    const float* vals_t = (const float*)d_in[5];
    const float* gamma  = (const float*)d_in[6];

    float* out     = (float*)d_out;
    char*  ws      = (char*)d_ws;
    int*   cnt     = (int*)ws;                    // [NN*NSEG]
    float* rowsum  = (float*)(ws + RS_OFF);       // [NN]
    int*   ovf_cnt = (int*)(ws + OC_OFF);         // [1]
    Pair*  bucket  = (Pair*)(ws + BK_OFF);        // [NN*NSEG*SCAP]
    int4*  ovf     = (int4*)(ws + OV_OFF);        // [8192]

    // Zero cursors + rowsums + overflow counter in one memset (ws is 0xAA-poisoned).
    (void)hipMemsetAsync(ws, 0, OC_OFF + 4, stream);

    fill_kernel<<<TOTAL / 256, 256, 0, stream>>>(rows_s, cols_s, vals_s,
                                                 rows_t, cols_t, vals_t,
                                                 gamma, cnt, rowsum, bucket,
                                                 ovf_cnt, ovf);
    row_kernel<<<NN * NSEG, 256, 0, stream>>>(cnt, rowsum, bucket,
                                              ovf_cnt, ovf, out);
}

// Round 9
// 310.087 us; speedup vs baseline: 1.0950x; 1.0950x over previous
//
#include <hip/hip_runtime.h>
#include <math.h>

#define NN 8192        // n_nodes
#define NE 262144      // edges per adjacency list
#define TOTAL (2*NE)   // 524288
#define CAP 128        // bucket capacity per row (mean 64, sd 8; max ~95)

typedef float f4 __attribute__((ext_vector_type(4)));

struct Pair { int c; float v; };

// Workspace layout (bytes):
//   [0, 32768)              cnt[8192] row cursors
//   [32768, 32772)          ovf_cnt
//   [65536, 65536+8MB)      bucket Pair[8192][128]
//   [65536+8MB, +128KB)     ovf int4[8192]  (r, c, bits(w*v), 0)
#define BK_OFF (65536)
#define OV_OFF (65536 + (size_t)NN * CAP * 8)

// Single-pass bucket build: ONE device atomic per edge (R7/R8 lesson: a second
// atomic per edge costs ~+28 us — fill is atomic-throughput-bound).
__global__ __launch_bounds__(256) void fill_kernel(
        const int* __restrict__ rows_s, const int* __restrict__ cols_s,
        const float* __restrict__ vals_s,
        const int* __restrict__ rows_t, const int* __restrict__ cols_t,
        const float* __restrict__ vals_t,
        const float* __restrict__ gamma,
        int* __restrict__ cnt, Pair* __restrict__ bucket,
        int* __restrict__ ovf_cnt, int4* __restrict__ ovf) {
    int i = blockIdx.x * blockDim.x + threadIdx.x;
    float alpha = 1.0f / (1.0f + expf(-gamma[0]));
    int r, c; float v, w;
    if (i < NE) { r = rows_s[i]; c = cols_s[i]; v = vals_s[i]; w = alpha; }
    else { int j = i - NE; r = rows_t[j]; c = cols_t[j]; v = vals_t[j]; w = 1.0f - alpha; }
    float wv = w * v;
    int pos = atomicAdd(&cnt[r], 1);
    if (pos < CAP) {
        Pair p; p.c = c; p.v = wv;
        bucket[r * CAP + pos] = p;
    } else {  // statistically unreachable at these sizes; kept for correctness
        int k = atomicAdd(ovf_cnt, 1);
        int4 e; e.x = r; e.y = c; e.z = __float_as_int(wv); e.w = 0;
        ovf[k] = e;
    }
}

// One block per row (R4 structure — best measured). Row sum is reduced from
// the row's bucket values in-block (same addend multiset as the reference's
// dense row sum, reordered); costs nothing vs. the write-bound store phase.
__global__ __launch_bounds__(256) void row_kernel(
        const int* __restrict__ cnt, const Pair* __restrict__ bucket,
        const int* __restrict__ ovf_cnt, const int4* __restrict__ ovf,
        float* __restrict__ out) {
    __shared__ float row[NN];          // 32 KB -> 5 blocks/CU (neutral vs 8, R6)
    __shared__ float red[4];
    int r = blockIdx.x;
    int t = threadIdx.x;

    int no = *ovf_cnt;                 // hoisted: overlaps LDS-zero latency
    f4* row4 = (f4*)row;
    #pragma unroll
    for (int k = t; k < NN / 4; k += 256) { f4 z = {0.f, 0.f, 0.f, 0.f}; row4[k] = z; }
    int n = cnt[r];
    int nb = n < CAP ? n : CAP;
    __syncthreads();

    float part = 0.0f;
    for (int k = t; k < nb; k += 256) {
        Pair p = bucket[r * CAP + k];
        part += p.v;
        atomicAdd(&row[p.c], p.v);
    }
    if (no > 0) {                      // cold path, normally 0 entries
        for (int k = t; k < no; k += 256) {
            int4 e = ovf[k];
            if (e.x == r) {
                float v = __int_as_float(e.z);
                part += v;
                atomicAdd(&row[e.y], v);
            }
        }
    }

    #pragma unroll
    for (int o = 32; o > 0; o >>= 1) part += __shfl_down(part, o, 64);
    if ((t & 63) == 0) red[t >> 6] = part;
    __syncthreads();                   // fences LDS atomics + red[] writes
    float total = red[0] + red[1] + red[2] + red[3];
    float inv = (total == 0.0f) ? 1.0f : 1.0f / total;

    f4* out4 = (f4*)(out + (size_t)r * NN);
    #pragma unroll
    for (int k = t; k < NN / 4; k += 256) {
        f4 x = row4[k];
        x *= inv;
        __builtin_nontemporal_store(x, &out4[k]);
    }
}

extern "C" void kernel_launch(void* const* d_in, const int* in_sizes, int n_in,
                              void* d_out, int out_size, void* d_ws, size_t ws_size,
                              hipStream_t stream) {
    const int*   rows_s = (const int*)  d_in[0];
    const int*   cols_s = (const int*)  d_in[1];
    const float* vals_s = (const float*)d_in[2];
    const int*   rows_t = (const int*)  d_in[3];
    const int*   cols_t = (const int*)  d_in[4];
    const float* vals_t = (const float*)d_in[5];
    const float* gamma  = (const float*)d_in[6];

    float* out     = (float*)d_out;
    char*  ws      = (char*)d_ws;
    int*   cnt     = (int*)ws;                    // [NN]
    int*   ovf_cnt = (int*)(ws + 32768);          // [1]
    Pair*  bucket  = (Pair*)(ws + BK_OFF);        // [NN*CAP]
    int4*  ovf     = (int4*)(ws + OV_OFF);        // [8192]

    // Zero cursors + overflow counter (ws is poisoned with 0xAA).
    (void)hipMemsetAsync(ws, 0, 32772, stream);

    fill_kernel<<<TOTAL / 256, 256, 0, stream>>>(rows_s, cols_s, vals_s,
                                                 rows_t, cols_t, vals_t,
                                                 gamma, cnt, bucket, ovf_cnt, ovf);
    row_kernel<<<NN, 256, 0, stream>>>(cnt, bucket, ovf_cnt, ovf, out);
}